// Round 16
// baseline (237.075 us; speedup 1.0000x reference)
//
#include <hip/hip_runtime.h>
#include <hip/hip_bf16.h>
#include <stdint.h>

// ---------- types & helpers ----------
typedef float f32x4 __attribute__((ext_vector_type(4)));
typedef __bf16 bf16x8 __attribute__((ext_vector_type(8)));

__device__ __forceinline__ unsigned short f2bf(float f) {
    union { float f; unsigned u; } v; v.f = f;
    unsigned r = v.u + 0x7fffu + ((v.u >> 16) & 1u);
    return (unsigned short)(r >> 16);
}
__device__ __forceinline__ float bf2f(unsigned short u) {
    union { unsigned u; float f; } v; v.u = ((unsigned)u) << 16;
    return v.f;
}
__device__ __forceinline__ unsigned cvt_pk_bf16(float lo, float hi) {
    unsigned r;
    asm("v_cvt_pk_bf16_f32 %0, %1, %2" : "=v"(r) : "v"(lo), "v"(hi));
    return r;
}

// global -> LDS async copy, 16B per lane. LDS dest must be linear in lane order.
__device__ __forceinline__ void gl_lds16(const void* g, void* l) {
    __builtin_amdgcn_global_load_lds(
        (const __attribute__((address_space(1))) void*)(unsigned long long)(uintptr_t)g,
        (__attribute__((address_space(3))) void*)(unsigned)(uintptr_t)l,
        16, 0, 0);
}

// 2-D supertile mapping: XCD chunk (nwg/8 consecutive swz) covers a GRxGC
// rectangle of tiles so co-resident blocks share A-slices GC-way and
// B-slices GR-way in the XCD's private L2 (K-slice lockstep reuse).
__device__ __forceinline__ void tile_map(int bid, int nwg, int nbx, int GR, int GC,
                                         int* bx, int* by) {
    const int swz = (bid & 7) * (nwg >> 3) + (bid >> 3);
    const int CH = nwg >> 3;
    const int chunk = swz / CH, ii = swz % CH;
    const int KC = nbx / GC;
    *bx = (chunk % KC) * GC + (ii % GC);
    *by = (chunk / KC) * GR + (ii / GC);
}

// ---------- fp32 -> bf16 weight conversion ----------
__global__ __launch_bounds__(256) void cvt_kernel(const float* __restrict__ in,
                                                  unsigned short* __restrict__ outp) {
    int i = blockIdx.x * 256 + threadIdx.x;
    float4 v = ((const float4*)in)[i];
    ushort4 o;
    o.x = f2bf(v.x); o.y = f2bf(v.y); o.z = f2bf(v.z); o.w = f2bf(v.w);
    ((ushort4*)outp)[i] = o;
}

// ---------- LayerNorm (row=1024) fp32 in -> bf16 out ----------
__global__ __launch_bounds__(256) void ln_kernel(const float* __restrict__ x,
                                                 const float* __restrict__ g,
                                                 const float* __restrict__ b,
                                                 unsigned short* __restrict__ outp) {
    const int row = blockIdx.x;
    const int t = threadIdx.x;
    const float4 v = ((const float4*)(x + (size_t)row * 1024))[t];
    float s = v.x + v.y + v.z + v.w;
    float s2 = v.x * v.x + v.y * v.y + v.z * v.z + v.w * v.w;
    #pragma unroll
    for (int off = 1; off < 64; off <<= 1) {
        s  += __shfl_xor(s, off);
        s2 += __shfl_xor(s2, off);
    }
    __shared__ float red[8];
    const int w = t >> 6;
    if ((t & 63) == 0) { red[w * 2] = s; red[w * 2 + 1] = s2; }
    __syncthreads();
    s  = red[0] + red[2] + red[4] + red[6];
    s2 = red[1] + red[3] + red[5] + red[7];
    const float mu = s * (1.0f / 1024.0f);
    const float var = s2 * (1.0f / 1024.0f) - mu * mu;
    const float rstd = rsqrtf(var + 1e-5f);
    const float4 gv = ((const float4*)g)[t];
    const float4 bv = ((const float4*)b)[t];
    ushort4 o;
    o.x = f2bf((v.x - mu) * rstd * gv.x + bv.x);
    o.y = f2bf((v.y - mu) * rstd * gv.y + bv.y);
    o.z = f2bf((v.z - mu) * rstd * gv.z + bv.z);
    o.w = f2bf((v.w - mu) * rstd * gv.w + bv.w);
    ((ushort4*)(outp + (size_t)row * 1024))[t] = o;
}

// ---------- RoPE + head-layout repack (Q, K only) ----------
__global__ __launch_bounds__(512) void rope_kernel(const unsigned short* __restrict__ qkv,
                                                   const float* __restrict__ rc,
                                                   const float* __restrict__ rs,
                                                   unsigned short* __restrict__ Qr,
                                                   unsigned short* __restrict__ Kr) {
    const int sb = blockIdx.x;           // s*4 + b
    const int s = sb >> 2, b = sb & 3;
    const int t = threadIdx.x;
    const int h = t >> 5, d = t & 31;
    const size_t rowo = (size_t)sb * 3072;
    const float c = rc[s * 32 + d];
    const float sn = rs[s * 32 + d];
    const size_t ho = ((size_t)(b * 16 + h) * 1024 + s) * 64;

    const float q1 = bf2f(qkv[rowo + h * 64 + d]);
    const float q2 = bf2f(qkv[rowo + h * 64 + d + 32]);
    Qr[ho + d]      = f2bf((q1 * c - q2 * sn) * 0.125f);
    Qr[ho + d + 32] = f2bf((q1 * sn + q2 * c) * 0.125f);

    const float k1 = bf2f(qkv[rowo + 1024 + h * 64 + d]);
    const float k2 = bf2f(qkv[rowo + 1024 + h * 64 + d + 32]);
    Kr[ho + d]      = f2bf(k1 * c - k2 * sn);
    Kr[ho + d + 32] = f2bf(k1 * sn + k2 * c);
}

// ---------- V^T repack: qkv V-part -> Vt (b,h,d,s) ----------
__global__ __launch_bounds__(256) void vt_kernel(const unsigned short* __restrict__ qkv,
                                                 unsigned short* __restrict__ Vt) {
    __shared__ unsigned short t[64][66];
    const int s0 = blockIdx.x * 64;
    const int bh = blockIdx.y;
    const int b = bh >> 4, h = bh & 15;
    const int tid = threadIdx.x;
    const int si = tid >> 3, c = (tid & 7) * 8;
    #pragma unroll
    for (int r = 0; r < 2; r++) {
        const int s = si + r * 32;
        union { uint4 u; unsigned short sh[8]; } v;
        v.u = *(const uint4*)&qkv[((size_t)(s0 + s) * 4 + b) * 3072 + 2048 + h * 64 + c];
        #pragma unroll
        for (int i = 0; i < 8; i++) t[c + i][s] = v.sh[i];
    }
    __syncthreads();
    #pragma unroll
    for (int r = 0; r < 2; r++) {
        const int d = si + r * 32;
        const unsigned* rp = (const unsigned*)((const char*)&t[0][0] + d * 132 + c * 2);
        uint4 ov;
        ov.x = rp[0]; ov.y = rp[1]; ov.z = rp[2]; ov.w = rp[3];
        *(uint4*)&Vt[((size_t)bh * 64 + d) * 1024 + s0 + c] = ov;
    }
}

// ---------- GEMM Z: 256^2, 8 waves, m201-style 4-phase/K-tile schedule ----------
// Per phase: {ds_read quadrant + stage half-tile of next K-tile} BEFORE the
// barrier (cross-wave LDS/MFMA overlap), then s_barrier, lgkmcnt(0),
// setprio-wrapped 16 MFMA, s_barrier.  Boundary vmcnt(0) sits >=1 phase after
// the newest gl_lds issue (P3 stages the last 2 half-tiles), so the drain is
// near-free.  Double-buffered 128 KB LDS, 1 block/CU, T2 swizzled staging.
template <int EPI, int GR, int GC>
__global__ __launch_bounds__(512, 2)
void gemmZ(const unsigned short* __restrict__ A, const unsigned short* __restrict__ Bw,
           const float* __restrict__ bias, const float* __restrict__ res,
           void* __restrict__ Cout, int N, int K, int nbx) {
    constexpr int ASZ = 256 * 64;   // one K-tile of A (or B): 32 KB
    __shared__ __attribute__((aligned(16))) unsigned short As[2 * ASZ];
    __shared__ __attribute__((aligned(16))) unsigned short Bs[2 * ASZ];

    int bx, by;
    tile_map(blockIdx.x, gridDim.x, nbx, GR, GC, &bx, &by);
    const int bm = by * 256, bn = bx * 256;

    const int tid = threadIdx.x;
    const int w = tid >> 6, l = tid & 63;
    const int wr = w >> 2, wc = w & 3;          // 2M x 4N waves; wave out 128x64
    const int lm = l & 15, lg = l >> 4, lx = lm & 7;

    // T2: pre-swizzled global source column; linear LDS dest
    const int srow = tid >> 3;                  // 0..63
    const int sgx = ((tid & 7) ^ (srow & 7)) * 8;
    const int sdst = (tid & 7) * 8;
    const unsigned short* Ag = A + (size_t)(bm + srow) * K + sgx;
    const unsigned short* Bg = Bw + (size_t)(bn + srow) * K + sgx;

    const int c0 = ((lg ^ lx) << 3);
    const int c1 = (((4 + lg) ^ lx) << 3);

    f32x4 acc[8][4];
    #pragma unroll
    for (int i = 0; i < 8; i++)
        #pragma unroll
        for (int j = 0; j < 4; j++) acc[i][j] = f32x4{0.f, 0.f, 0.f, 0.f};

    // stage half-tile h (128 rows = 2 gl_lds) of A or B for tile at k0
    auto SA = [&](int buf, int k0, int h) {
        gl_lds16(Ag + (size_t)(h * 128) * K + k0,      &As[buf * ASZ + (h * 128 + srow) * 64 + sdst]);
        gl_lds16(Ag + (size_t)(h * 128 + 64) * K + k0, &As[buf * ASZ + (h * 128 + 64 + srow) * 64 + sdst]);
    };
    auto SB = [&](int buf, int k0, int h) {
        gl_lds16(Bg + (size_t)(h * 128) * K + k0,      &Bs[buf * ASZ + (h * 128 + srow) * 64 + sdst]);
        gl_lds16(Bg + (size_t)(h * 128 + 64) * K + k0, &Bs[buf * ASZ + (h * 128 + 64 + srow) * 64 + sdst]);
    };

    // prologue: tile 0 fully staged
    SA(0, 0, 0); SB(0, 0, 0); SA(0, 0, 1); SB(0, 0, 1);
    asm volatile("s_waitcnt vmcnt(0)" ::: "memory");
    __builtin_amdgcn_s_barrier();

    const int NT = K >> 6;
    const int arow0 = wr * 128 + lm;
    const int brow0 = wc * 64 + lm;
    int cur = 0;

    for (int t = 0; t < NT; ++t) {
        const int ab = cur * ASZ, bb = cur * ASZ;
        const int nk0 = (t + 1) << 6;
        const bool pf = (t + 1 < NT);
        bf16x8 bfrag[4], afrag[4];

        // ---- P1: B(c0) + A(mi0-3,c0); stage next HA0 ----
        #pragma unroll
        for (int ni = 0; ni < 4; ni++)
            bfrag[ni] = *(const bf16x8*)&Bs[bb + (brow0 + ni * 16) * 64 + c0];
        #pragma unroll
        for (int mi = 0; mi < 4; mi++)
            afrag[mi] = *(const bf16x8*)&As[ab + (arow0 + mi * 16) * 64 + c0];
        if (pf) SA(cur ^ 1, nk0, 0);
        __builtin_amdgcn_sched_barrier(0);
        __builtin_amdgcn_s_barrier();
        asm volatile("s_waitcnt lgkmcnt(0)" ::: "memory");
        __builtin_amdgcn_sched_barrier(0);
        __builtin_amdgcn_s_setprio(1);
        #pragma unroll
        for (int mi = 0; mi < 4; mi++)
            #pragma unroll
            for (int ni = 0; ni < 4; ni++)
                acc[mi][ni] = __builtin_amdgcn_mfma_f32_16x16x32_bf16(afrag[mi], bfrag[ni], acc[mi][ni], 0, 0, 0);
        __builtin_amdgcn_s_setprio(0);
        __builtin_amdgcn_s_barrier();

        // ---- P2: A(mi4-7,c0); stage next HB0 ----
        #pragma unroll
        for (int mi = 0; mi < 4; mi++)
            afrag[mi] = *(const bf16x8*)&As[ab + (arow0 + 64 + mi * 16) * 64 + c0];
        if (pf) SB(cur ^ 1, nk0, 0);
        __builtin_amdgcn_sched_barrier(0);
        __builtin_amdgcn_s_barrier();
        asm volatile("s_waitcnt lgkmcnt(0)" ::: "memory");
        __builtin_amdgcn_sched_barrier(0);
        __builtin_amdgcn_s_setprio(1);
        #pragma unroll
        for (int mi = 0; mi < 4; mi++)
            #pragma unroll
            for (int ni = 0; ni < 4; ni++)
                acc[mi + 4][ni] = __builtin_amdgcn_mfma_f32_16x16x32_bf16(afrag[mi], bfrag[ni], acc[mi + 4][ni], 0, 0, 0);
        __builtin_amdgcn_s_setprio(0);
        __builtin_amdgcn_s_barrier();

        // ---- P3: B(c1) + A(mi0-3,c1); stage next HA1+HB1 ----
        #pragma unroll
        for (int ni = 0; ni < 4; ni++)
            bfrag[ni] = *(const bf16x8*)&Bs[bb + (brow0 + ni * 16) * 64 + c1];
        #pragma unroll
        for (int mi = 0; mi < 4; mi++)
            afrag[mi] = *(const bf16x8*)&As[ab + (arow0 + mi * 16) * 64 + c1];
        if (pf) { SA(cur ^ 1, nk0, 1); SB(cur ^ 1, nk0, 1); }
        __builtin_amdgcn_sched_barrier(0);
        __builtin_amdgcn_s_barrier();
        asm volatile("s_waitcnt lgkmcnt(0)" ::: "memory");
        __builtin_amdgcn_sched_barrier(0);
        __builtin_amdgcn_s_setprio(1);
        #pragma unroll
        for (int mi = 0; mi < 4; mi++)
            #pragma unroll
            for (int ni = 0; ni < 4; ni++)
                acc[mi][ni] = __builtin_amdgcn_mfma_f32_16x16x32_bf16(afrag[mi], bfrag[ni], acc[mi][ni], 0, 0, 0);
        __builtin_amdgcn_s_setprio(0);
        __builtin_amdgcn_s_barrier();

        // ---- P4: A(mi4-7,c1); boundary vmcnt(0) (newest issue ~1 phase old) ----
        #pragma unroll
        for (int mi = 0; mi < 4; mi++)
            afrag[mi] = *(const bf16x8*)&As[ab + (arow0 + 64 + mi * 16) * 64 + c1];
        __builtin_amdgcn_sched_barrier(0);
        __builtin_amdgcn_s_barrier();
        asm volatile("s_waitcnt lgkmcnt(0)" ::: "memory");
        __builtin_amdgcn_sched_barrier(0);
        __builtin_amdgcn_s_setprio(1);
        #pragma unroll
        for (int mi = 0; mi < 4; mi++)
            #pragma unroll
            for (int ni = 0; ni < 4; ni++)
                acc[mi + 4][ni] = __builtin_amdgcn_mfma_f32_16x16x32_bf16(afrag[mi], bfrag[ni], acc[mi + 4][ni], 0, 0, 0);
        __builtin_amdgcn_s_setprio(0);
        asm volatile("s_waitcnt vmcnt(0)" ::: "memory");
        __builtin_amdgcn_s_barrier();

        cur ^= 1;
    }

    const int r0 = bm + wr * 128 + lg * 4;
    #pragma unroll
    for (int ni = 0; ni < 4; ni++) {
        const int col = bn + wc * 64 + ni * 16 + lm;
        const float bc = bias[col];
        #pragma unroll
        for (int mi = 0; mi < 8; mi++) {
            #pragma unroll
            for (int j = 0; j < 4; j++) {
                const int row = r0 + mi * 16 + j;
                const size_t idx = (size_t)row * N + col;
                const float v = acc[mi][ni][j] + bc;
                if constexpr (EPI == 0) {
                    ((unsigned short*)Cout)[idx] = f2bf(v);
                } else if constexpr (EPI == 2) {
                    const float ge = 0.5f * v * (1.0f + erff(v * 0.70710678118654752f));
                    ((unsigned short*)Cout)[idx] = f2bf(ge);
                } else {
                    ((float*)Cout)[idx] = v + res[idx];
                }
            }
        }
    }
}

// ---------- GEMM v4 (128^2, counted-vmcnt, raw barriers) for N=1024 GEMMs ----------
template <int EPI, int GR, int GC>
__global__ __launch_bounds__(256, 2)
void gemm4(const unsigned short* __restrict__ A, const unsigned short* __restrict__ Bw,
           const float* __restrict__ bias, const float* __restrict__ res,
           void* __restrict__ Cout, int N, int K, int nbx) {
    constexpr int ASZ = 128 * 64, BSZ = 128 * 64;
    __shared__ __attribute__((aligned(16))) unsigned short As[2 * ASZ];
    __shared__ __attribute__((aligned(16))) unsigned short Bs[2 * BSZ];

    int bx, by;
    tile_map(blockIdx.x, gridDim.x, nbx, GR, GC, &bx, &by);
    const int bm = by * 128, bn = bx * 128;

    const int tid = threadIdx.x;
    const int w = tid >> 6, l = tid & 63;
    const int wr = w >> 1, wc = w & 1;
    const int lm = l & 15, lg = l >> 4, lx = lm & 7;

    const int srow = tid >> 3;
    const int sgx = ((tid & 7) ^ (srow & 7)) * 8;
    const unsigned short* Ag = A + (size_t)(bm + srow) * K + sgx;
    const unsigned short* Bg = Bw + (size_t)(bn + srow) * K + sgx;

    const int c0 = ((lg ^ lx) << 3);
    const int c1 = (((4 + lg) ^ lx) << 3);

    f32x4 acc[4][4];
    #pragma unroll
    for (int i = 0; i < 4; i++)
        #pragma unroll
        for (int j = 0; j < 4; j++) acc[i][j] = f32x4{0.f, 0.f, 0.f, 0.f};

    auto STAGE = [&](int buf, int k0) {
        #pragma unroll
        for (int i = 0; i < 4; i++)
            gl_lds16(Ag + (size_t)i * 32 * K + k0, &As[buf * ASZ + i * 32 * 64 + tid * 8]);
        #pragma unroll
        for (int i = 0; i < 4; i++)
            gl_lds16(Bg + (size_t)i * 32 * K + k0, &Bs[buf * BSZ + i * 32 * 64 + tid * 8]);
    };

    const int NT = K >> 6;
    STAGE(0, 0);
    STAGE(1, 64);

    int cur = 0;
    for (int t = 0; t < NT; ++t) {
        if (t + 1 < NT) asm volatile("s_waitcnt vmcnt(8)" ::: "memory");
        else            asm volatile("s_waitcnt vmcnt(0)" ::: "memory");
        __builtin_amdgcn_s_barrier();
        asm volatile("" ::: "memory");

        const int ab = cur * ASZ, bb = cur * BSZ;
        #pragma unroll
        for (int h = 0; h < 2; h++) {
            const int cc = h ? c1 : c0;
            bf16x8 af[4], bfr[4];
            #pragma unroll
            for (int mi = 0; mi < 4; mi++)
                af[mi] = *(const bf16x8*)&As[ab + (wr * 64 + mi * 16 + lm) * 64 + cc];
            #pragma unroll
            for (int ni = 0; ni < 4; ni++)
                bfr[ni] = *(const bf16x8*)&Bs[bb + (wc * 64 + ni * 16 + lm) * 64 + cc];
            __builtin_amdgcn_s_setprio(1);
            #pragma unroll
            for (int mi = 0; mi < 4; mi++)
                #pragma unroll
                for (int ni = 0; ni < 4; ni++)
                    acc[mi][ni] = __builtin_amdgcn_mfma_f32_16x16x32_bf16(
                        af[mi], bfr[ni], acc[mi][ni], 0, 0, 0);
            __builtin_amdgcn_s_setprio(0);
        }

        asm volatile("" ::: "memory");
        __builtin_amdgcn_s_barrier();
        asm volatile("" ::: "memory");
        if (t + 2 < NT) STAGE(cur, (t + 2) << 6);
        cur ^= 1;
    }

    const int r0 = bm + wr * 64 + lg * 4;
    #pragma unroll
    for (int ni = 0; ni < 4; ni++) {
        const int col = bn + wc * 64 + ni * 16 + lm;
        const float bc = bias[col];
        #pragma unroll
        for (int mi = 0; mi < 4; mi++) {
            #pragma unroll
            for (int j = 0; j < 4; j++) {
                const int row = r0 + mi * 16 + j;
                const size_t idx = (size_t)row * N + col;
                const float v = acc[mi][ni][j] + bc;
                if constexpr (EPI == 0) {
                    ((unsigned short*)Cout)[idx] = f2bf(v);
                } else if constexpr (EPI == 2) {
                    const float ge = 0.5f * v * (1.0f + erff(v * 0.70710678118654752f));
                    ((unsigned short*)Cout)[idx] = f2bf(ge);
                } else {
                    ((float*)Cout)[idx] = v + res[idx];
                }
            }
        }
    }
}

// ---------- fused attention: KVBLK=64, head-clustered XCD mapping ----------
__global__ __launch_bounds__(256, 4)
void attn_kernel(const unsigned short* __restrict__ Qr, const unsigned short* __restrict__ Kr,
                 const unsigned short* __restrict__ Vt, unsigned short* __restrict__ AO) {
    __shared__ __attribute__((aligned(16))) unsigned short Ks[64][72];  // kv x d
    __shared__ __attribute__((aligned(16))) unsigned short Vs[64][72];  // d x kv
    const int swz = ((blockIdx.x & 7) << 7) + (blockIdx.x >> 3);  // nwg=1024
    const int bh = swz >> 4, qt = swz & 15;
    const int tid = threadIdx.x;
    const int w = tid >> 6, l = tid & 63;
    const int lm = l & 15, lg = l >> 4;
    const size_t hoff = (size_t)bh * (1024 * 64);

    const size_t qrow = hoff + (size_t)(qt * 64 + w * 16 + lm) * 64;
    const bf16x8 qf0 = *(const bf16x8*)&Qr[qrow + lg * 8];
    const bf16x8 qf1 = *(const bf16x8*)&Qr[qrow + 32 + lg * 8];

    float m = -1e30f, lsum = 0.f;
    f32x4 acc[4];
    #pragma unroll
    for (int i = 0; i < 4; i++) acc[i] = f32x4{0.f, 0.f, 0.f, 0.f};

    const int sr = tid >> 3, scc = (tid & 7) * 8;
    const int srcA = lm + 16 * ((2 * lg) & 3);
    const int srcB = lm + 16 * ((2 * lg + 1) & 3);
    const bool hi2 = (lg & 2) != 0;

    uint4 kr0 = *(const uint4*)&Kr[hoff + (size_t)sr * 64 + scc];
    uint4 kr1 = *(const uint4*)&Kr[hoff + (size_t)(sr + 32) * 64 + scc];
    uint4 vr0 = *(const uint4*)&Vt[hoff + (size_t)sr * 1024 + scc];
    uint4 vr1 = *(const uint4*)&Vt[hoff + (size_t)(sr + 32) * 1024 + scc];

    for (int kt = 0; kt < 16; kt++) {
        __syncthreads();
        *(uint4*)&Ks[sr][scc]      = kr0;
        *(uint4*)&Ks[sr + 32][scc] = kr1;
        *(uint4*)&Vs[sr][scc]      = vr0;
        *(uint4*)&Vs[sr + 32][scc] = vr1;
        __syncthreads();
        if (kt < 15) {
            const size_t kb = hoff + (size_t)(kt + 1) * 64 * 64;
            kr0 = *(const uint4*)&Kr[kb + (size_t)sr * 64 + scc];
            kr1 = *(const uint4*)&Kr[kb + (size_t)(sr + 32) * 64 + scc];
            vr0 = *(const uint4*)&Vt[hoff + (size_t)sr * 1024 + (kt + 1) * 64 + scc];
            vr1 = *(const uint4*)&Vt[hoff + (size_t)(sr + 32) * 1024 + (kt + 1) * 64 + scc];
        }

        f32x4 st[4];
        #pragma unroll
        for (int nt = 0; nt < 4; nt++) {
            const bf16x8 kf0 = *(const bf16x8*)&Ks[nt * 16 + lm][lg * 8];
            const bf16x8 kf1 = *(const bf16x8*)&Ks[nt * 16 + lm][32 + lg * 8];
            f32x4 s = f32x4{0.f, 0.f, 0.f, 0.f};
            s = __builtin_amdgcn_mfma_f32_16x16x32_bf16(kf0, qf0, s, 0, 0, 0);
            s = __builtin_amdgcn_mfma_f32_16x16x32_bf16(kf1, qf1, s, 0, 0, 0);
            st[nt] = s;
        }

        float tmax = st[0][0];
        #pragma unroll
        for (int nt = 0; nt < 4; nt++)
            #pragma unroll
            for (int j = 0; j < 4; j++) tmax = fmaxf(tmax, st[nt][j]);
        tmax = fmaxf(tmax, __shfl_xor(tmax, 16));
        tmax = fmaxf(tmax, __shfl_xor(tmax, 32));

        const float mnew = fmaxf(m, tmax);
        const float fac = __builtin_amdgcn_exp2f((m - mnew) * 1.4426950408889634f);
        m = mnew;

        unsigned pd[4][2];
        float rsum = 0.f;
        #pragma unroll
        for (int nt = 0; nt < 4; nt++) {
            const float p0 = __builtin_amdgcn_exp2f((st[nt][0] - mnew) * 1.4426950408889634f);
            const float p1 = __builtin_amdgcn_exp2f((st[nt][1] - mnew) * 1.4426950408889634f);
            const float p2 = __builtin_amdgcn_exp2f((st[nt][2] - mnew) * 1.4426950408889634f);
            const float p3 = __builtin_amdgcn_exp2f((st[nt][3] - mnew) * 1.4426950408889634f);
            rsum += (p0 + p1) + (p2 + p3);
            pd[nt][0] = cvt_pk_bf16(p0, p1);
            pd[nt][1] = cvt_pk_bf16(p2, p3);
        }
        rsum += __shfl_xor(rsum, 16);
        rsum += __shfl_xor(rsum, 32);
        lsum = lsum * fac + rsum;
        #pragma unroll
        for (int nt2 = 0; nt2 < 4; nt2++)
            #pragma unroll
            for (int j = 0; j < 4; j++) acc[nt2][j] *= fac;

        #pragma unroll
        for (int kt2 = 0; kt2 < 2; kt2++) {
            const int a0 = __shfl((int)pd[kt2 * 2][0], srcA);
            const int a1 = __shfl((int)pd[kt2 * 2 + 1][0], srcA);
            const int a2 = __shfl((int)pd[kt2 * 2][1], srcA);
            const int a3 = __shfl((int)pd[kt2 * 2 + 1][1], srcA);
            const int b0 = __shfl((int)pd[kt2 * 2][0], srcB);
            const int b1 = __shfl((int)pd[kt2 * 2 + 1][0], srcB);
            const int b2 = __shfl((int)pd[kt2 * 2][1], srcB);
            const int b3 = __shfl((int)pd[kt2 * 2 + 1][1], srcB);
            union { int u[4]; bf16x8 v; } pf;
            pf.u[0] = hi2 ? a1 : a0;
            pf.u[1] = hi2 ? a3 : a2;
            pf.u[2] = hi2 ? b1 : b0;
            pf.u[3] = hi2 ? b3 : b2;
            #pragma unroll
            for (int nt2 = 0; nt2 < 4; nt2++) {
                const bf16x8 vf = *(const bf16x8*)&Vs[nt2 * 16 + lm][kt2 * 32 + lg * 8];
                acc[nt2] = __builtin_amdgcn_mfma_f32_16x16x32_bf16(vf, pf.v, acc[nt2], 0, 0, 0);
            }
        }
    }

    const int b = bh >> 4, h = bh & 15;
    const float inv = 1.0f / lsum;
    const int s = qt * 64 + w * 16 + lm;
    #pragma unroll
    for (int nt2 = 0; nt2 < 4; nt2++) {
        ushort4 o;
        o.x = f2bf(acc[nt2][0] * inv);
        o.y = f2bf(acc[nt2][1] * inv);
        o.z = f2bf(acc[nt2][2] * inv);
        o.w = f2bf(acc[nt2][3] * inv);
        *(ushort4*)&AO[(size_t)(s * 4 + b) * 1024 + h * 64 + nt2 * 16 + lg * 4] = o;
    }
}

// ---------- host launcher ----------
extern "C" void kernel_launch(void* const* d_in, const int* in_sizes, int n_in,
                              void* d_out, int out_size, void* d_ws, size_t ws_size,
                              hipStream_t stream) {
    const float* q    = (const float*)d_in[0];
    const float* w_in = (const float*)d_in[1];
    const float* b_in = (const float*)d_in[2];
    const float* w_o  = (const float*)d_in[3];
    const float* b_o  = (const float*)d_in[4];
    const float* g1   = (const float*)d_in[5];
    const float* be1  = (const float*)d_in[6];
    const float* g2   = (const float*)d_in[7];
    const float* be2  = (const float*)d_in[8];
    const float* w1   = (const float*)d_in[9];
    const float* b1   = (const float*)d_in[10];
    const float* w2   = (const float*)d_in[11];
    const float* b2   = (const float*)d_in[12];
    const float* rc   = (const float*)d_in[13];
    const float* rsn  = (const float*)d_in[14];
    float* outp = (float*)d_out;

    char* base = (char*)d_ws;
    if (ws_size < 109051904ull) return;  // need ~104 MB

    unsigned short* wb_in  = (unsigned short*)(base + 0);
    unsigned short* wb_out = wb_in + 3145728;
    unsigned short* wb_ff1 = wb_out + 1048576;
    unsigned short* wb_ff2 = wb_ff1 + 4194304;
    unsigned short* xq  = (unsigned short*)(base + 25165824);
    unsigned short* qkv = (unsigned short*)(base + 33554432);
    unsigned short* hh  = (unsigned short*)(base + 33554432);
    unsigned short* Qr  = (unsigned short*)(base + 58720256);
    unsigned short* Kr  = (unsigned short*)(base + 67108864);
    unsigned short* Vt  = (unsigned short*)(base + 75497472);
    unsigned short* ao  = (unsigned short*)(base + 83886080);
    float*          x   = (float*)(base + 92274688);
    unsigned short* y   = xq;

    cvt_kernel<<<3072, 256, 0, stream>>>(w_in, wb_in);
    cvt_kernel<<<1024, 256, 0, stream>>>(w_o, wb_out);
    cvt_kernel<<<4096, 256, 0, stream>>>(w1, wb_ff1);
    cvt_kernel<<<4096, 256, 0, stream>>>(w2, wb_ff2);

    ln_kernel<<<4096, 256, 0, stream>>>(q, g1, be1, xq);
    // qkv: M=4096 N=3072 K=1024, 256^2 8-phase, grid 16x12=192, groups 8x3
    gemmZ<0, 8, 3><<<192, 512, 0, stream>>>(xq, wb_in, b_in, nullptr, qkv, 3072, 1024, 12);
    rope_kernel<<<4096, 512, 0, stream>>>(qkv, rc, rsn, Qr, Kr);
    vt_kernel<<<dim3(16, 64), 256, 0, stream>>>(qkv, Vt);
    attn_kernel<<<1024, 256, 0, stream>>>(Qr, Kr, Vt, ao);
    // out-proj: M=4096 N=1024 K=1024, 128^2, grid 256, groups 8x4
    gemm4<1, 8, 4><<<256, 256, 0, stream>>>(ao, wb_out, b_o, q, x, 1024, 1024, 8);
    ln_kernel<<<4096, 256, 0, stream>>>(x, g2, be2, y);
    // ff1: M=4096 N=4096 K=1024, 256^2 8-phase, grid 16x16=256, groups 8x4
    gemmZ<2, 8, 4><<<256, 512, 0, stream>>>(y, wb_ff1, b1, nullptr, hh, 4096, 1024, 16);
    // ff2: M=4096 N=1024 K=4096, 128^2, grid 256, groups 8x4
    gemm4<3, 8, 4><<<256, 256, 0, stream>>>(hh, wb_ff2, b2, x, outp, 1024, 4096, 8);
}

// Round 17
// 214.605 us; speedup vs baseline: 1.1047x; 1.1047x over previous
//
#include <hip/hip_runtime.h>
#include <hip/hip_bf16.h>
#include <stdint.h>

// ---------- types & helpers ----------
typedef float f32x4 __attribute__((ext_vector_type(4)));
typedef __bf16 bf16x8 __attribute__((ext_vector_type(8)));

__device__ __forceinline__ unsigned short f2bf(float f) {
    union { float f; unsigned u; } v; v.f = f;
    unsigned r = v.u + 0x7fffu + ((v.u >> 16) & 1u);
    return (unsigned short)(r >> 16);
}
__device__ __forceinline__ float bf2f(unsigned short u) {
    union { unsigned u; float f; } v; v.u = ((unsigned)u) << 16;
    return v.f;
}
__device__ __forceinline__ unsigned cvt_pk_bf16(float lo, float hi) {
    unsigned r;
    asm("v_cvt_pk_bf16_f32 %0, %1, %2" : "=v"(r) : "v"(lo), "v"(hi));
    return r;
}

// global -> LDS async copy, 16B per lane. LDS dest must be linear in lane order.
__device__ __forceinline__ void gl_lds16(const void* g, void* l) {
    __builtin_amdgcn_global_load_lds(
        (const __attribute__((address_space(1))) void*)(unsigned long long)(uintptr_t)g,
        (__attribute__((address_space(3))) void*)(unsigned)(uintptr_t)l,
        16, 0, 0);
}

// 2-D supertile mapping: XCD chunk (nwg/8 consecutive swz) covers a GRxGC
// rectangle of tiles so co-resident blocks share A-slices GC-way and
// B-slices GR-way in the XCD's private L2 (K-slice lockstep reuse).
__device__ __forceinline__ void tile_map(int bid, int nwg, int nbx, int GR, int GC,
                                         int* bx, int* by) {
    const int swz = (bid & 7) * (nwg >> 3) + (bid >> 3);
    const int CH = nwg >> 3;
    const int chunk = swz / CH, ii = swz % CH;
    const int KC = nbx / GC;
    *bx = (chunk % KC) * GC + (ii % GC);
    *by = (chunk / KC) * GR + (ii / GC);
}

// ---------- fp32 -> bf16 weight conversion ----------
__global__ __launch_bounds__(256) void cvt_kernel(const float* __restrict__ in,
                                                  unsigned short* __restrict__ outp) {
    int i = blockIdx.x * 256 + threadIdx.x;
    float4 v = ((const float4*)in)[i];
    ushort4 o;
    o.x = f2bf(v.x); o.y = f2bf(v.y); o.z = f2bf(v.z); o.w = f2bf(v.w);
    ((ushort4*)outp)[i] = o;
}

// ---------- LayerNorm (row=1024) fp32 in -> bf16 out ----------
__global__ __launch_bounds__(256) void ln_kernel(const float* __restrict__ x,
                                                 const float* __restrict__ g,
                                                 const float* __restrict__ b,
                                                 unsigned short* __restrict__ outp) {
    const int row = blockIdx.x;
    const int t = threadIdx.x;
    const float4 v = ((const float4*)(x + (size_t)row * 1024))[t];
    float s = v.x + v.y + v.z + v.w;
    float s2 = v.x * v.x + v.y * v.y + v.z * v.z + v.w * v.w;
    #pragma unroll
    for (int off = 1; off < 64; off <<= 1) {
        s  += __shfl_xor(s, off);
        s2 += __shfl_xor(s2, off);
    }
    __shared__ float red[8];
    const int w = t >> 6;
    if ((t & 63) == 0) { red[w * 2] = s; red[w * 2 + 1] = s2; }
    __syncthreads();
    s  = red[0] + red[2] + red[4] + red[6];
    s2 = red[1] + red[3] + red[5] + red[7];
    const float mu = s * (1.0f / 1024.0f);
    const float var = s2 * (1.0f / 1024.0f) - mu * mu;
    const float rstd = rsqrtf(var + 1e-5f);
    const float4 gv = ((const float4*)g)[t];
    const float4 bv = ((const float4*)b)[t];
    ushort4 o;
    o.x = f2bf((v.x - mu) * rstd * gv.x + bv.x);
    o.y = f2bf((v.y - mu) * rstd * gv.y + bv.y);
    o.z = f2bf((v.z - mu) * rstd * gv.z + bv.z);
    o.w = f2bf((v.w - mu) * rstd * gv.w + bv.w);
    ((ushort4*)(outp + (size_t)row * 1024))[t] = o;
}

// ---------- RoPE + head-layout repack (Q, K only) ----------
__global__ __launch_bounds__(512) void rope_kernel(const unsigned short* __restrict__ qkv,
                                                   const float* __restrict__ rc,
                                                   const float* __restrict__ rs,
                                                   unsigned short* __restrict__ Qr,
                                                   unsigned short* __restrict__ Kr) {
    const int sb = blockIdx.x;           // s*4 + b
    const int s = sb >> 2, b = sb & 3;
    const int t = threadIdx.x;
    const int h = t >> 5, d = t & 31;
    const size_t rowo = (size_t)sb * 3072;
    const float c = rc[s * 32 + d];
    const float sn = rs[s * 32 + d];
    const size_t ho = ((size_t)(b * 16 + h) * 1024 + s) * 64;

    const float q1 = bf2f(qkv[rowo + h * 64 + d]);
    const float q2 = bf2f(qkv[rowo + h * 64 + d + 32]);
    Qr[ho + d]      = f2bf((q1 * c - q2 * sn) * 0.125f);
    Qr[ho + d + 32] = f2bf((q1 * sn + q2 * c) * 0.125f);

    const float k1 = bf2f(qkv[rowo + 1024 + h * 64 + d]);
    const float k2 = bf2f(qkv[rowo + 1024 + h * 64 + d + 32]);
    Kr[ho + d]      = f2bf(k1 * c - k2 * sn);
    Kr[ho + d + 32] = f2bf(k1 * sn + k2 * c);
}

// ---------- V^T repack: qkv V-part -> Vt (b,h,d,s) ----------
__global__ __launch_bounds__(256) void vt_kernel(const unsigned short* __restrict__ qkv,
                                                 unsigned short* __restrict__ Vt) {
    __shared__ unsigned short t[64][66];
    const int s0 = blockIdx.x * 64;
    const int bh = blockIdx.y;
    const int b = bh >> 4, h = bh & 15;
    const int tid = threadIdx.x;
    const int si = tid >> 3, c = (tid & 7) * 8;
    #pragma unroll
    for (int r = 0; r < 2; r++) {
        const int s = si + r * 32;
        union { uint4 u; unsigned short sh[8]; } v;
        v.u = *(const uint4*)&qkv[((size_t)(s0 + s) * 4 + b) * 3072 + 2048 + h * 64 + c];
        #pragma unroll
        for (int i = 0; i < 8; i++) t[c + i][s] = v.sh[i];
    }
    __syncthreads();
    #pragma unroll
    for (int r = 0; r < 2; r++) {
        const int d = si + r * 32;
        const unsigned* rp = (const unsigned*)((const char*)&t[0][0] + d * 132 + c * 2);
        uint4 ov;
        ov.x = rp[0]; ov.y = rp[1]; ov.z = rp[2]; ov.w = rp[3];
        *(uint4*)&Vt[((size_t)bh * 64 + d) * 1024 + s0 + c] = ov;
    }
}

// ---------- GEMM W: 256x128 tile, 8 waves, single-buffer, 2 blocks/CU ----------
template <int EPI, int GR, int GC>
__global__ __launch_bounds__(512, 4)
void gemmW(const unsigned short* __restrict__ A, const unsigned short* __restrict__ Bw,
           const float* __restrict__ bias, unsigned short* __restrict__ Cout,
           int N, int K, int nbx) {
    __shared__ __attribute__((aligned(16))) unsigned short smem[32768];  // 64 KB
    unsigned short* As = smem;            // [256][64]
    unsigned short* Bs = smem + 16384;    // [128][64]

    int bx, by;
    tile_map(blockIdx.x, gridDim.x, nbx, GR, GC, &bx, &by);
    const int bm = by * 256, bn = bx * 128;

    const int tid = threadIdx.x;
    const int w = tid >> 6, l = tid & 63;
    const int wr = w >> 2, wc = w & 3;          // 2M x 4N waves; wave tile 128x32
    const int lm = l & 15, lg = l >> 4, lx = lm & 7;

    const int srow = tid >> 3;
    const int sgx = ((tid & 7) ^ (srow & 7)) * 8;
    const int sdst = (tid & 7) * 8;
    const unsigned short* Ag = A + (size_t)(bm + srow) * K + sgx;
    const unsigned short* Bg = Bw + (size_t)(bn + srow) * K + sgx;

    const int c0 = ((lg ^ lx) << 3);
    const int c1 = (((4 + lg) ^ lx) << 3);

    f32x4 acc[8][2];
    #pragma unroll
    for (int i = 0; i < 8; i++)
        #pragma unroll
        for (int j = 0; j < 2; j++) acc[i][j] = f32x4{0.f, 0.f, 0.f, 0.f};

    const int arow = wr * 128 + lm;
    const int brow = wc * 32 + lm;

    for (int k0 = 0; k0 < K; k0 += 64) {
        __syncthreads();
        #pragma unroll
        for (int i = 0; i < 4; i++)
            gl_lds16(Ag + (size_t)(i * 64) * K + k0, &As[(srow + i * 64) * 64 + sdst]);
        #pragma unroll
        for (int i = 0; i < 2; i++)
            gl_lds16(Bg + (size_t)(i * 64) * K + k0, &Bs[(srow + i * 64) * 64 + sdst]);
        __syncthreads();
        #pragma unroll
        for (int h = 0; h < 2; h++) {
            const int cc = h ? c1 : c0;
            bf16x8 af[8], bfr[2];
            #pragma unroll
            for (int ni = 0; ni < 2; ni++)
                bfr[ni] = *(const bf16x8*)&Bs[(brow + ni * 16) * 64 + cc];
            #pragma unroll
            for (int mi = 0; mi < 8; mi++)
                af[mi] = *(const bf16x8*)&As[(arow + mi * 16) * 64 + cc];
            #pragma unroll
            for (int mi = 0; mi < 8; mi++)
                #pragma unroll
                for (int ni = 0; ni < 2; ni++)
                    acc[mi][ni] = __builtin_amdgcn_mfma_f32_16x16x32_bf16(
                        af[mi], bfr[ni], acc[mi][ni], 0, 0, 0);
        }
    }

    // ---- coalesced epilogue: acc -> LDS [256][128] bf16 -> 256B row writes ----
    __syncthreads();
    const int r0l = wr * 128 + lg * 4;
    #pragma unroll
    for (int ni = 0; ni < 2; ni++) {
        const int col = wc * 32 + ni * 16 + lm;
        const float bc = bias[bn + col];
        #pragma unroll
        for (int mi = 0; mi < 8; mi++) {
            #pragma unroll
            for (int j = 0; j < 4; j++) {
                const int row = r0l + mi * 16 + j;
                float v = acc[mi][ni][j] + bc;
                if constexpr (EPI == 2)
                    v = 0.5f * v * (1.0f + erff(v * 0.70710678118654752f));
                smem[row * 128 + col] = f2bf(v);
            }
        }
    }
    __syncthreads();
    const int orow = tid >> 4, oseg = (tid & 15) * 8;
    #pragma unroll
    for (int p = 0; p < 8; p++) {
        const int row = p * 32 + orow;
        const uint4 v = *(const uint4*)&smem[row * 128 + oseg];
        *(uint4*)&Cout[(size_t)(bm + row) * N + bn + oseg] = v;
    }
}

// ---------- GEMM v4 (shape-templated, counted-vmcnt, raw barriers) ----------
// BM x BN tile, 4 waves (WM x WN each), 2 blocks/CU when grid >= 512.
template <int EPI, int BM, int BN, int WM, int WN, int GR, int GC>
__global__ __launch_bounds__(256, 2)
void gemm4(const unsigned short* __restrict__ A, const unsigned short* __restrict__ Bw,
           const float* __restrict__ bias, const float* __restrict__ res,
           void* __restrict__ Cout, int N, int K, int nbx) {
    constexpr int ASZ = BM * 64, BSZ = BN * 64;
    constexpr int LPS = BM / 32 + BN / 32;      // gl_lds issues per STAGE
    constexpr int WAVES_N = BN / WN;
    constexpr int MR = WM / 16, NR = WN / 16;
    __shared__ __attribute__((aligned(16))) unsigned short As[2 * ASZ];
    __shared__ __attribute__((aligned(16))) unsigned short Bs[2 * BSZ];

    int bx, by;
    tile_map(blockIdx.x, gridDim.x, nbx, GR, GC, &bx, &by);
    const int bm = by * BM, bn = bx * BN;

    const int tid = threadIdx.x;
    const int w = tid >> 6, l = tid & 63;
    const int wr = w / WAVES_N, wc = w % WAVES_N;
    const int lm = l & 15, lg = l >> 4, lx = lm & 7;

    const int srow = tid >> 3;
    const int sgx = ((tid & 7) ^ (srow & 7)) * 8;
    const unsigned short* Ag = A + (size_t)(bm + srow) * K + sgx;
    const unsigned short* Bg = Bw + (size_t)(bn + srow) * K + sgx;

    const int c0 = ((lg ^ lx) << 3);
    const int c1 = (((4 + lg) ^ lx) << 3);

    f32x4 acc[MR][NR];
    #pragma unroll
    for (int i = 0; i < MR; i++)
        #pragma unroll
        for (int j = 0; j < NR; j++) acc[i][j] = f32x4{0.f, 0.f, 0.f, 0.f};

    auto STAGE = [&](int buf, int k0) {
        #pragma unroll
        for (int i = 0; i < BM / 32; i++)
            gl_lds16(Ag + (size_t)i * 32 * K + k0, &As[buf * ASZ + i * 32 * 64 + tid * 8]);
        #pragma unroll
        for (int i = 0; i < BN / 32; i++)
            gl_lds16(Bg + (size_t)i * 32 * K + k0, &Bs[buf * BSZ + i * 32 * 64 + tid * 8]);
    };

    const int NT = K >> 6;
    STAGE(0, 0);
    STAGE(1, 64);

    int cur = 0;
    for (int t = 0; t < NT; ++t) {
        if (t + 1 < NT) {
            if constexpr (LPS == 6) asm volatile("s_waitcnt vmcnt(6)" ::: "memory");
            else                    asm volatile("s_waitcnt vmcnt(8)" ::: "memory");
        } else {
            asm volatile("s_waitcnt vmcnt(0)" ::: "memory");
        }
        __builtin_amdgcn_s_barrier();
        asm volatile("" ::: "memory");

        const int ab = cur * ASZ, bb = cur * BSZ;
        #pragma unroll
        for (int h = 0; h < 2; h++) {
            const int cc = h ? c1 : c0;
            bf16x8 af[MR], bfr[NR];
            #pragma unroll
            for (int mi = 0; mi < MR; mi++)
                af[mi] = *(const bf16x8*)&As[ab + (wr * WM + mi * 16 + lm) * 64 + cc];
            #pragma unroll
            for (int ni = 0; ni < NR; ni++)
                bfr[ni] = *(const bf16x8*)&Bs[bb + (wc * WN + ni * 16 + lm) * 64 + cc];
            __builtin_amdgcn_s_setprio(1);
            #pragma unroll
            for (int mi = 0; mi < MR; mi++)
                #pragma unroll
                for (int ni = 0; ni < NR; ni++)
                    acc[mi][ni] = __builtin_amdgcn_mfma_f32_16x16x32_bf16(
                        af[mi], bfr[ni], acc[mi][ni], 0, 0, 0);
            __builtin_amdgcn_s_setprio(0);
        }

        asm volatile("" ::: "memory");
        __builtin_amdgcn_s_barrier();
        asm volatile("" ::: "memory");
        if (t + 2 < NT) STAGE(cur, (t + 2) << 6);
        cur ^= 1;
    }

    const int r0 = bm + wr * WM + lg * 4;
    #pragma unroll
    for (int ni = 0; ni < NR; ni++) {
        const int col = bn + wc * WN + ni * 16 + lm;
        const float bc = bias[col];
        #pragma unroll
        for (int mi = 0; mi < MR; mi++) {
            #pragma unroll
            for (int j = 0; j < 4; j++) {
                const int row = r0 + mi * 16 + j;
                const size_t idx = (size_t)row * N + col;
                const float v = acc[mi][ni][j] + bc;
                if constexpr (EPI == 0) {
                    ((unsigned short*)Cout)[idx] = f2bf(v);
                } else if constexpr (EPI == 2) {
                    const float ge = 0.5f * v * (1.0f + erff(v * 0.70710678118654752f));
                    ((unsigned short*)Cout)[idx] = f2bf(ge);
                } else {
                    ((float*)Cout)[idx] = v + res[idx];
                }
            }
        }
    }
}

// ---------- fused attention: KVBLK=64, head-clustered XCD mapping ----------
__global__ __launch_bounds__(256, 4)
void attn_kernel(const unsigned short* __restrict__ Qr, const unsigned short* __restrict__ Kr,
                 const unsigned short* __restrict__ Vt, unsigned short* __restrict__ AO) {
    __shared__ __attribute__((aligned(16))) unsigned short Ks[64][72];  // kv x d
    __shared__ __attribute__((aligned(16))) unsigned short Vs[64][72];  // d x kv
    const int swz = ((blockIdx.x & 7) << 7) + (blockIdx.x >> 3);  // nwg=1024
    const int bh = swz >> 4, qt = swz & 15;
    const int tid = threadIdx.x;
    const int w = tid >> 6, l = tid & 63;
    const int lm = l & 15, lg = l >> 4;
    const size_t hoff = (size_t)bh * (1024 * 64);

    const size_t qrow = hoff + (size_t)(qt * 64 + w * 16 + lm) * 64;
    const bf16x8 qf0 = *(const bf16x8*)&Qr[qrow + lg * 8];
    const bf16x8 qf1 = *(const bf16x8*)&Qr[qrow + 32 + lg * 8];

    float m = -1e30f, lsum = 0.f;
    f32x4 acc[4];
    #pragma unroll
    for (int i = 0; i < 4; i++) acc[i] = f32x4{0.f, 0.f, 0.f, 0.f};

    const int sr = tid >> 3, scc = (tid & 7) * 8;
    const int srcA = lm + 16 * ((2 * lg) & 3);
    const int srcB = lm + 16 * ((2 * lg + 1) & 3);
    const bool hi2 = (lg & 2) != 0;

    uint4 kr0 = *(const uint4*)&Kr[hoff + (size_t)sr * 64 + scc];
    uint4 kr1 = *(const uint4*)&Kr[hoff + (size_t)(sr + 32) * 64 + scc];
    uint4 vr0 = *(const uint4*)&Vt[hoff + (size_t)sr * 1024 + scc];
    uint4 vr1 = *(const uint4*)&Vt[hoff + (size_t)(sr + 32) * 1024 + scc];

    for (int kt = 0; kt < 16; kt++) {
        __syncthreads();
        *(uint4*)&Ks[sr][scc]      = kr0;
        *(uint4*)&Ks[sr + 32][scc] = kr1;
        *(uint4*)&Vs[sr][scc]      = vr0;
        *(uint4*)&Vs[sr + 32][scc] = vr1;
        __syncthreads();
        if (kt < 15) {
            const size_t kb = hoff + (size_t)(kt + 1) * 64 * 64;
            kr0 = *(const uint4*)&Kr[kb + (size_t)sr * 64 + scc];
            kr1 = *(const uint4*)&Kr[kb + (size_t)(sr + 32) * 64 + scc];
            vr0 = *(const uint4*)&Vt[hoff + (size_t)sr * 1024 + (kt + 1) * 64 + scc];
            vr1 = *(const uint4*)&Vt[hoff + (size_t)(sr + 32) * 1024 + (kt + 1) * 64 + scc];
        }

        f32x4 st[4];
        #pragma unroll
        for (int nt = 0; nt < 4; nt++) {
            const bf16x8 kf0 = *(const bf16x8*)&Ks[nt * 16 + lm][lg * 8];
            const bf16x8 kf1 = *(const bf16x8*)&Ks[nt * 16 + lm][32 + lg * 8];
            f32x4 s = f32x4{0.f, 0.f, 0.f, 0.f};
            s = __builtin_amdgcn_mfma_f32_16x16x32_bf16(kf0, qf0, s, 0, 0, 0);
            s = __builtin_amdgcn_mfma_f32_16x16x32_bf16(kf1, qf1, s, 0, 0, 0);
            st[nt] = s;
        }

        float tmax = st[0][0];
        #pragma unroll
        for (int nt = 0; nt < 4; nt++)
            #pragma unroll
            for (int j = 0; j < 4; j++) tmax = fmaxf(tmax, st[nt][j]);
        tmax = fmaxf(tmax, __shfl_xor(tmax, 16));
        tmax = fmaxf(tmax, __shfl_xor(tmax, 32));

        const float mnew = fmaxf(m, tmax);
        const float fac = __builtin_amdgcn_exp2f((m - mnew) * 1.4426950408889634f);
        m = mnew;

        unsigned pd[4][2];
        float rsum = 0.f;
        #pragma unroll
        for (int nt = 0; nt < 4; nt++) {
            const float p0 = __builtin_amdgcn_exp2f((st[nt][0] - mnew) * 1.4426950408889634f);
            const float p1 = __builtin_amdgcn_exp2f((st[nt][1] - mnew) * 1.4426950408889634f);
            const float p2 = __builtin_amdgcn_exp2f((st[nt][2] - mnew) * 1.4426950408889634f);
            const float p3 = __builtin_amdgcn_exp2f((st[nt][3] - mnew) * 1.4426950408889634f);
            rsum += (p0 + p1) + (p2 + p3);
            pd[nt][0] = cvt_pk_bf16(p0, p1);
            pd[nt][1] = cvt_pk_bf16(p2, p3);
        }
        rsum += __shfl_xor(rsum, 16);
        rsum += __shfl_xor(rsum, 32);
        lsum = lsum * fac + rsum;
        #pragma unroll
        for (int nt2 = 0; nt2 < 4; nt2++)
            #pragma unroll
            for (int j = 0; j < 4; j++) acc[nt2][j] *= fac;

        #pragma unroll
        for (int kt2 = 0; kt2 < 2; kt2++) {
            const int a0 = __shfl((int)pd[kt2 * 2][0], srcA);
            const int a1 = __shfl((int)pd[kt2 * 2 + 1][0], srcA);
            const int a2 = __shfl((int)pd[kt2 * 2][1], srcA);
            const int a3 = __shfl((int)pd[kt2 * 2 + 1][1], srcA);
            const int b0 = __shfl((int)pd[kt2 * 2][0], srcB);
            const int b1 = __shfl((int)pd[kt2 * 2 + 1][0], srcB);
            const int b2 = __shfl((int)pd[kt2 * 2][1], srcB);
            const int b3 = __shfl((int)pd[kt2 * 2 + 1][1], srcB);
            union { int u[4]; bf16x8 v; } pf;
            pf.u[0] = hi2 ? a1 : a0;
            pf.u[1] = hi2 ? a3 : a2;
            pf.u[2] = hi2 ? b1 : b0;
            pf.u[3] = hi2 ? b3 : b2;
            #pragma unroll
            for (int nt2 = 0; nt2 < 4; nt2++) {
                const bf16x8 vf = *(const bf16x8*)&Vs[nt2 * 16 + lm][kt2 * 32 + lg * 8];
                acc[nt2] = __builtin_amdgcn_mfma_f32_16x16x32_bf16(vf, pf.v, acc[nt2], 0, 0, 0);
            }
        }
    }

    const int b = bh >> 4, h = bh & 15;
    const float inv = 1.0f / lsum;
    const int s = qt * 64 + w * 16 + lm;
    #pragma unroll
    for (int nt2 = 0; nt2 < 4; nt2++) {
        ushort4 o;
        o.x = f2bf(acc[nt2][0] * inv);
        o.y = f2bf(acc[nt2][1] * inv);
        o.z = f2bf(acc[nt2][2] * inv);
        o.w = f2bf(acc[nt2][3] * inv);
        *(ushort4*)&AO[(size_t)(s * 4 + b) * 1024 + h * 64 + nt2 * 16 + lg * 4] = o;
    }
}

// ---------- host launcher ----------
extern "C" void kernel_launch(void* const* d_in, const int* in_sizes, int n_in,
                              void* d_out, int out_size, void* d_ws, size_t ws_size,
                              hipStream_t stream) {
    const float* q    = (const float*)d_in[0];
    const float* w_in = (const float*)d_in[1];
    const float* b_in = (const float*)d_in[2];
    const float* w_o  = (const float*)d_in[3];
    const float* b_o  = (const float*)d_in[4];
    const float* g1   = (const float*)d_in[5];
    const float* be1  = (const float*)d_in[6];
    const float* g2   = (const float*)d_in[7];
    const float* be2  = (const float*)d_in[8];
    const float* w1   = (const float*)d_in[9];
    const float* b1   = (const float*)d_in[10];
    const float* w2   = (const float*)d_in[11];
    const float* b2   = (const float*)d_in[12];
    const float* rc   = (const float*)d_in[13];
    const float* rsn  = (const float*)d_in[14];
    float* outp = (float*)d_out;

    char* base = (char*)d_ws;
    if (ws_size < 109051904ull) return;  // need ~104 MB

    unsigned short* wb_in  = (unsigned short*)(base + 0);
    unsigned short* wb_out = wb_in + 3145728;
    unsigned short* wb_ff1 = wb_out + 1048576;
    unsigned short* wb_ff2 = wb_ff1 + 4194304;
    unsigned short* xq  = (unsigned short*)(base + 25165824);
    unsigned short* qkv = (unsigned short*)(base + 33554432);
    unsigned short* hh  = (unsigned short*)(base + 33554432);
    unsigned short* Qr  = (unsigned short*)(base + 58720256);
    unsigned short* Kr  = (unsigned short*)(base + 67108864);
    unsigned short* Vt  = (unsigned short*)(base + 75497472);
    unsigned short* ao  = (unsigned short*)(base + 83886080);
    float*          x   = (float*)(base + 92274688);
    unsigned short* y   = xq;

    cvt_kernel<<<3072, 256, 0, stream>>>(w_in, wb_in);
    cvt_kernel<<<1024, 256, 0, stream>>>(w_o, wb_out);
    cvt_kernel<<<4096, 256, 0, stream>>>(w1, wb_ff1);
    cvt_kernel<<<4096, 256, 0, stream>>>(w2, wb_ff2);

    ln_kernel<<<4096, 256, 0, stream>>>(q, g1, be1, xq);
    // qkv: M=4096 N=3072 K=1024, 256x128 tiles, grid 384, groups 8x6
    gemmW<0, 8, 6><<<384, 512, 0, stream>>>(xq, wb_in, b_in, qkv, 3072, 1024, 24);
    rope_kernel<<<4096, 512, 0, stream>>>(qkv, rc, rsn, Qr, Kr);
    vt_kernel<<<dim3(16, 64), 256, 0, stream>>>(qkv, Vt);
    attn_kernel<<<1024, 256, 0, stream>>>(Qr, Kr, Vt, ao);
    // out-proj: M=4096 N=1024 K=1024, 128x64 tiles, grid 32x16=512 (2 blk/CU), groups 8x8
    gemm4<1, 128, 64, 64, 32, 8, 8><<<512, 256, 0, stream>>>(ao, wb_out, b_o, q, x, 1024, 1024, 16);
    ln_kernel<<<4096, 256, 0, stream>>>(x, g2, be2, y);
    // ff1: M=4096 N=4096 K=1024, 256x128 tiles, grid 512, groups 8x8
    gemmW<2, 8, 8><<<512, 512, 0, stream>>>(y, wb_ff1, b1, hh, 4096, 1024, 32);
    // ff2: M=4096 N=1024 K=4096, 128x64 tiles, grid 32x16=512 (2 blk/CU), groups 8x8
    gemm4<3, 128, 64, 64, 32, 8, 8><<<512, 256, 0, stream>>>(hh, wb_ff2, b2, x, outp, 1024, 4096, 16);
}